// Round 3
// baseline (158.218 us; speedup 1.0000x reference)
//
#include <hip/hip_runtime.h>
#include <hip/hip_bf16.h>
#include <math.h>

#define NP 1024          // proposals
#define NC 81            // classes incl background
#define CF 80            // foreground classes
#define DET 100          // detections per image
#define SCORE_THRESH 0.05f
#define NMS_THRESH 0.5f
#define BBOX_CLIP 4.135166556742356f   // log(1000/16)
#define IMG_W 1333
#define IMG_H 800

#define NCAND (CF * DET)   // 8000 max compacted candidates

// ---------------------------------------------------------------------------
// Kernel 1: per-proposal softmax scores only (decode moved to kernel 2).
// One 64-lane wave per proposal, 4 proposals per 256-thread block.
// scores_fg class-major [c][i] (coalesced row loads in kernel 2).
// Also zeroes: d_out (block 0), gK (block 0), gkeys[0..NCAND) (all blocks).
// ---------------------------------------------------------------------------
__global__ __launch_bounds__(256) void
softmax_kernel(const float* __restrict__ logits,
               float* __restrict__ scores_fg,
               unsigned long long* __restrict__ gkeys,
               float* __restrict__ out,
               int* __restrict__ gK) {
    // zero pass (gkeys must be 0 so kernel 3's padded rank loop is inert)
    {
        const int gid = blockIdx.x * 256 + threadIdx.x;   // 0..65535
        if (gid < NCAND) gkeys[gid] = 0ull;
    }
    if (blockIdx.x == 0) {
        for (int t = threadIdx.x; t < 6 * DET; t += 256) out[t] = 0.0f;
        if (threadIdx.x == 0) *gK = 0;
    }

    const int wave = threadIdx.x >> 6;
    const int lane = threadIdx.x & 63;
    const int i = blockIdx.x * 4 + wave;          // proposal index

    // softmax over 81 logits: lane holds x0 = logit[lane], x1 = logit[64+lane]
    const float x0 = logits[i * NC + lane];
    const float x1 = (lane < NC - 64) ? logits[i * NC + 64 + lane] : -INFINITY;

    float m = fmaxf(x0, x1);
    for (int off = 32; off > 0; off >>= 1) m = fmaxf(m, __shfl_xor(m, off));

    const float e0 = expf(x0 - m);
    const float e1 = (lane < NC - 64) ? expf(x1 - m) : 0.0f;
    float sum = e0 + e1;
    for (int off = 32; off > 0; off >>= 1) sum += __shfl_xor(sum, off);

    // write fg scores, class-major
    if (lane >= 1) scores_fg[(lane - 1) * NP + i] = e0 / sum;          // c=lane
    if (lane < NC - 64) scores_fg[(64 + lane - 1) * NP + i] = e1 / sum; // c=64+lane
}

// ---------------------------------------------------------------------------
// Kernel 2: per-class threshold-compact -> u64-key bitonic sort -> on-demand
// box decode -> greedy NMS -> append kept (<=DET) to global candidate list.
// Single wave (64 threads) per class block: barriers are ~free.
// Within-class sort key: (score_bits<<16)|(1023-id)  == (score desc, id asc).
// Global key: (score_bits<<16)|(65535-slot), slot = cls*DET + keptRank:
// order-isomorphic to the reference's (score desc, flat-index asc) tie-break.
// ---------------------------------------------------------------------------
__global__ __launch_bounds__(64) void
class_nms_kernel(const float* __restrict__ scores_fg,
                 const float* __restrict__ rel,
                 const float* __restrict__ props,
                 unsigned long long* __restrict__ gkeys,
                 float4* __restrict__ gboxes,
                 int* __restrict__ gK) {
    const int cls = blockIdx.x;   // fg class (reference class = cls+1)
    const int tid = threadIdx.x;  // 0..63

    __shared__ unsigned long long key[NP];
    __shared__ float4             vbox[NP];
    __shared__ unsigned char      supp[NP];
    __shared__ int                cntSh;
    __shared__ int                keptRank[DET];
    __shared__ int                keptCnt;
    __shared__ int                baseSh;

    if (tid == 0) cntSh = 0;
    __syncthreads();

    // threshold compaction: 1024 scores, 4 float4 per lane
    const float4* srow = (const float4*)(scores_fg + cls * NP);
    #pragma unroll
    for (int k = 0; k < 4; ++k) {
        const int idx4 = k * 64 + tid;
        const float4 v = srow[idx4];
        const int id0 = idx4 * 4;
        if (v.x > SCORE_THRESH) { int p = atomicAdd(&cntSh, 1); key[p] = ((unsigned long long)__float_as_uint(v.x) << 16) | (unsigned long long)(1023 - (id0 + 0)); }
        if (v.y > SCORE_THRESH) { int p = atomicAdd(&cntSh, 1); key[p] = ((unsigned long long)__float_as_uint(v.y) << 16) | (unsigned long long)(1023 - (id0 + 1)); }
        if (v.z > SCORE_THRESH) { int p = atomicAdd(&cntSh, 1); key[p] = ((unsigned long long)__float_as_uint(v.z) << 16) | (unsigned long long)(1023 - (id0 + 2)); }
        if (v.w > SCORE_THRESH) { int p = atomicAdd(&cntSh, 1); key[p] = ((unsigned long long)__float_as_uint(v.w) << 16) | (unsigned long long)(1023 - (id0 + 3)); }
    }
    __syncthreads();
    const int cnt = cntSh;

    // next pow2 >= cnt, pad with 0 (sorts last: real keys have score bits set)
    int msz = 1;
    while (msz < cnt) msz <<= 1;
    for (int t = cnt + tid; t < msz; t += 64) key[t] = 0ull;
    __syncthreads();

    // bitonic sort descending (u64 key encodes score desc, id asc)
    for (int k = 2; k <= msz; k <<= 1) {
        for (int jj = k >> 1; jj > 0; jj >>= 1) {
            for (int t = tid; t < msz; t += 64) {
                const int ixj = t ^ jj;
                if (ixj > t) {
                    const unsigned long long a = key[t], b = key[ixj];
                    const bool tAfter = (a < b);              // desc order
                    const bool dirAsc = ((t & k) == 0);
                    if (dirAsc ? tAfter : !tAfter) { key[t] = b; key[ixj] = a; }
                }
            }
            __syncthreads();
        }
    }

    // on-demand box decode for the cnt survivors (exact reference formulas)
    for (int t = tid; t < cnt; t += 64) {
        const int id = 1023 - (int)(key[t] & 0xFFFFull);     // proposal index
        const float4 p = ((const float4*)props)[id];
        const float w  = p.z - p.x + 1.0f;
        const float h  = p.w - p.y + 1.0f;
        const float cx = p.x + 0.5f * w;
        const float cy = p.y + 0.5f * h;

        const float4 r = ((const float4*)rel)[id * NC + (cls + 1)];
        const float dx = r.x / 10.0f;
        const float dy = r.y / 10.0f;
        const float dw = fminf(r.z / 5.0f, BBOX_CLIP);
        const float dh = fminf(r.w / 5.0f, BBOX_CLIP);

        const float pcx = dx * w + cx;
        const float pcy = dy * h + cy;
        const float pw  = expf(dw) * w;
        const float ph  = expf(dh) * h;

        float bx1 = pcx - 0.5f * pw;
        float by1 = pcy - 0.5f * ph;
        float bx2 = pcx + 0.5f * pw - 1.0f;
        float by2 = pcy + 0.5f * ph - 1.0f;

        bx1 = fminf(fmaxf(bx1, 0.0f), (float)(IMG_W - 1));
        bx2 = fminf(fmaxf(bx2, 0.0f), (float)(IMG_W - 1));
        by1 = fminf(fmaxf(by1, 0.0f), (float)(IMG_H - 1));
        by2 = fminf(fmaxf(by2, 0.0f), (float)(IMG_H - 1));

        vbox[t] = make_float4(bx1, by1, bx2, by2);
        supp[t] = 0;
    }
    __syncthreads();

    // greedy NMS (legacy +1 IoU): sequential over i, parallel over j>i
    for (int i = 0; i < cnt; ++i) {
        if (!supp[i]) {
            const float4 bi = vbox[i];
            const float areai = (bi.z - bi.x + 1.0f) * (bi.w - bi.y + 1.0f);
            for (int t = i + 1 + tid; t < cnt; t += 64) {
                const float4 bj = vbox[t];
                const float areaj = (bj.z - bj.x + 1.0f) * (bj.w - bj.y + 1.0f);
                const float ltx = fmaxf(bi.x, bj.x);
                const float lty = fmaxf(bi.y, bj.y);
                const float rbx = fminf(bi.z, bj.z);
                const float rby = fminf(bi.w, bj.w);
                const float wq = fmaxf(rbx - ltx + 1.0f, 0.0f);
                const float hq = fmaxf(rby - lty + 1.0f, 0.0f);
                const float inter = wq * hq;
                const float iou = inter / (areai + areaj - inter);
                if (iou > NMS_THRESH) supp[t] = 1;
            }
        }
        __syncthreads();
    }

    // compact kept in rank order, cap at DET (lossless for global top-DET)
    if (tid == 0) {
        int c2 = 0;
        for (int r = 0; r < cnt && c2 < DET; ++r)
            if (!supp[r]) keptRank[c2++] = r;
        keptCnt = c2;
        baseSh = atomicAdd(gK, c2);     // device-scope reserve
    }
    __syncthreads();

    const int kc = keptCnt, base = baseSh;
    for (int t = tid; t < kc; t += 64) {
        const int r = keptRank[t];
        const int slot = cls * DET + t;
        const unsigned int bits = (unsigned int)(key[r] >> 16);  // score bits
        gkeys[base + t] = ((unsigned long long)bits << 16) |
                          (unsigned long long)(65535 - slot);
        gboxes[base + t] = vbox[r];
    }
}

// ---------------------------------------------------------------------------
// Kernel 3: rank-count top-DET over K compacted candidates, no LDS.
// Keys are block-uniform reads (scalar-cache friendly), 8-way unrolled so the
// loads pipeline instead of forming a dependent latency chain (the R2 bug).
// gkeys[K..NCAND) is zero (kernel 1), so looping to Kpad is inert.
// Ranks are dense & unique -> each out slot gets exactly one writer.
// ---------------------------------------------------------------------------
__global__ __launch_bounds__(64) void
topk_out_kernel(const unsigned long long* __restrict__ gkeys,
                const float4* __restrict__ gboxes,
                const int* __restrict__ gK,
                float* __restrict__ out) {
    const int K = *gK;
    const int g = blockIdx.x * 64 + threadIdx.x;
    if (g >= K) return;

    const unsigned long long my = gkeys[g];
    const int Kpad = (K + 7) & ~7;
    int rank = 0;
    for (int j = 0; j < Kpad; j += 8) {
        #pragma unroll
        for (int u = 0; u < 8; ++u)
            rank += (gkeys[j + u] > my) ? 1 : 0;
    }

    if (rank < DET) {
        const float sc  = __uint_as_float((unsigned)(my >> 16));
        const int  slot = 65535 - (int)(my & 0xFFFFull);
        const float4 b = gboxes[g];
        out[rank * 4 + 0] = b.x;
        out[rank * 4 + 1] = b.y;
        out[rank * 4 + 2] = b.z;
        out[rank * 4 + 3] = b.w;
        out[4 * DET + rank] = sc;                       // score (>0 always)
        out[5 * DET + rank] = (float)(slot / DET + 1);  // label
    }
}

// ---------------------------------------------------------------------------
extern "C" void kernel_launch(void* const* d_in, const int* in_sizes, int n_in,
                              void* d_out, int out_size, void* d_ws, size_t ws_size,
                              hipStream_t stream) {
    (void)in_sizes; (void)n_in; (void)out_size; (void)ws_size;

    const float* class_logits   = (const float*)d_in[0];  // [NP, NC]
    const float* box_regression = (const float*)d_in[1];  // [NP, 4*NC]
    const float* proposals      = (const float*)d_in[2];  // [NP, 4]
    float* out = (float*)d_out;                           // 600 floats

    // Workspace layout (float units; all offsets 16B-aligned)
    float* ws        = (float*)d_ws;
    float* gboxes_f  = ws;                                    // NCAND*4 = 32000
    float* gkeys_f   = gboxes_f + (size_t)NCAND * 4;          // NCAND*2 = 16000
    float* scores_fg = gkeys_f + (size_t)NCAND * 2;           // CF*NP   = 81920
    int*   gK        = (int*)(scores_fg + (size_t)CF * NP);   // 1

    unsigned long long* gkeys = (unsigned long long*)gkeys_f;
    float4* gboxes = (float4*)gboxes_f;

    softmax_kernel<<<dim3(NP / 4), dim3(256), 0, stream>>>(
        class_logits, scores_fg, gkeys, out, gK);

    class_nms_kernel<<<dim3(CF), dim3(64), 0, stream>>>(
        scores_fg, box_regression, proposals, gkeys, gboxes, gK);

    topk_out_kernel<<<dim3((NCAND + 63) / 64), dim3(64), 0, stream>>>(
        gkeys, gboxes, gK, out);
}

// Round 4
// 125.645 us; speedup vs baseline: 1.2592x; 1.2592x over previous
//
#include <hip/hip_runtime.h>
#include <hip/hip_bf16.h>
#include <math.h>

#define NP 1024          // proposals
#define NC 81            // classes incl background
#define CF 80            // foreground classes
#define DET 100          // detections per image
#define SCORE_THRESH 0.05f
#define NMS_THRESH 0.5f
#define BBOX_CLIP 4.135166556742356f   // log(1000/16)
#define IMG_W 1333
#define IMG_H 800

#define NCAND (CF * DET)   // 8000 fixed candidate slots

// ---------------------------------------------------------------------------
// Kernel 1: per-proposal softmax scores. One wave per proposal, 4/block.
// scores_fg class-major [c][i]. Block 0 zeroes d_out (harness re-poisons it).
// ---------------------------------------------------------------------------
__global__ __launch_bounds__(256) void
softmax_kernel(const float* __restrict__ logits,
               float* __restrict__ scores_fg,
               float* __restrict__ out) {
    if (blockIdx.x == 0) {
        for (int t = threadIdx.x; t < 6 * DET; t += 256) out[t] = 0.0f;
    }

    const int wave = threadIdx.x >> 6;
    const int lane = threadIdx.x & 63;
    const int i = blockIdx.x * 4 + wave;          // proposal index

    const float x0 = logits[i * NC + lane];
    const float x1 = (lane < NC - 64) ? logits[i * NC + 64 + lane] : -INFINITY;

    float m = fmaxf(x0, x1);
    for (int off = 32; off > 0; off >>= 1) m = fmaxf(m, __shfl_xor(m, off));

    const float e0 = expf(x0 - m);
    const float e1 = (lane < NC - 64) ? expf(x1 - m) : 0.0f;
    float sum = e0 + e1;
    for (int off = 32; off > 0; off >>= 1) sum += __shfl_xor(sum, off);

    if (lane >= 1) scores_fg[(lane - 1) * NP + i] = e0 / sum;
    if (lane < NC - 64) scores_fg[(64 + lane - 1) * NP + i] = e1 / sum;
}

// ---------------------------------------------------------------------------
// Kernel 2: per-class threshold-compact -> u64-key bitonic sort -> on-demand
// box decode -> greedy NMS -> write kept (<=DET) to FIXED slots
// gkeys[cls*DET+r] / gboxes[cls*DET+r], gcnt[cls]=count. No global atomics.
// Key = (score_bits<<16)|(65535-slot): (score desc, slot asc) == the
// reference's (score desc, flat-index asc) tie-break, class-major.
// Single wave per class block.
// ---------------------------------------------------------------------------
__global__ __launch_bounds__(64) void
class_nms_kernel(const float* __restrict__ scores_fg,
                 const float* __restrict__ rel,
                 const float* __restrict__ props,
                 unsigned long long* __restrict__ gkeys,
                 float4* __restrict__ gboxes,
                 int* __restrict__ gcnt) {
    const int cls = blockIdx.x;   // fg class (reference class = cls+1)
    const int tid = threadIdx.x;  // 0..63

    __shared__ unsigned long long key[NP];
    __shared__ float4             vbox[NP];
    __shared__ unsigned char      supp[NP];
    __shared__ int                cntSh;
    __shared__ int                keptRank[DET];
    __shared__ int                keptCnt;

    if (tid == 0) cntSh = 0;
    __syncthreads();

    // threshold compaction: 1024 scores, 4 float4 per lane
    const float4* srow = (const float4*)(scores_fg + cls * NP);
    #pragma unroll
    for (int k = 0; k < 4; ++k) {
        const int idx4 = k * 64 + tid;
        const float4 v = srow[idx4];
        const int id0 = idx4 * 4;
        if (v.x > SCORE_THRESH) { int p = atomicAdd(&cntSh, 1); key[p] = ((unsigned long long)__float_as_uint(v.x) << 16) | (unsigned long long)(1023 - (id0 + 0)); }
        if (v.y > SCORE_THRESH) { int p = atomicAdd(&cntSh, 1); key[p] = ((unsigned long long)__float_as_uint(v.y) << 16) | (unsigned long long)(1023 - (id0 + 1)); }
        if (v.z > SCORE_THRESH) { int p = atomicAdd(&cntSh, 1); key[p] = ((unsigned long long)__float_as_uint(v.z) << 16) | (unsigned long long)(1023 - (id0 + 2)); }
        if (v.w > SCORE_THRESH) { int p = atomicAdd(&cntSh, 1); key[p] = ((unsigned long long)__float_as_uint(v.w) << 16) | (unsigned long long)(1023 - (id0 + 3)); }
    }
    __syncthreads();
    const int cnt = cntSh;

    // next pow2 >= cnt, pad with 0 (real keys have score bits set -> sort last)
    int msz = 1;
    while (msz < cnt) msz <<= 1;
    for (int t = cnt + tid; t < msz; t += 64) key[t] = 0ull;
    __syncthreads();

    // bitonic sort descending (u64 key encodes score desc, id asc)
    for (int k = 2; k <= msz; k <<= 1) {
        for (int jj = k >> 1; jj > 0; jj >>= 1) {
            for (int t = tid; t < msz; t += 64) {
                const int ixj = t ^ jj;
                if (ixj > t) {
                    const unsigned long long a = key[t], b = key[ixj];
                    const bool tAfter = (a < b);              // desc order
                    const bool dirAsc = ((t & k) == 0);
                    if (dirAsc ? tAfter : !tAfter) { key[t] = b; key[ixj] = a; }
                }
            }
            __syncthreads();
        }
    }

    // on-demand box decode for survivors (exact reference formulas)
    for (int t = tid; t < cnt; t += 64) {
        const int id = 1023 - (int)(key[t] & 0xFFFFull);     // proposal index
        const float4 p = ((const float4*)props)[id];
        const float w  = p.z - p.x + 1.0f;
        const float h  = p.w - p.y + 1.0f;
        const float cx = p.x + 0.5f * w;
        const float cy = p.y + 0.5f * h;

        const float4 r = ((const float4*)rel)[id * NC + (cls + 1)];
        const float dx = r.x / 10.0f;
        const float dy = r.y / 10.0f;
        const float dw = fminf(r.z / 5.0f, BBOX_CLIP);
        const float dh = fminf(r.w / 5.0f, BBOX_CLIP);

        const float pcx = dx * w + cx;
        const float pcy = dy * h + cy;
        const float pw  = expf(dw) * w;
        const float ph  = expf(dh) * h;

        float bx1 = pcx - 0.5f * pw;
        float by1 = pcy - 0.5f * ph;
        float bx2 = pcx + 0.5f * pw - 1.0f;
        float by2 = pcy + 0.5f * ph - 1.0f;

        bx1 = fminf(fmaxf(bx1, 0.0f), (float)(IMG_W - 1));
        bx2 = fminf(fmaxf(bx2, 0.0f), (float)(IMG_W - 1));
        by1 = fminf(fmaxf(by1, 0.0f), (float)(IMG_H - 1));
        by2 = fminf(fmaxf(by2, 0.0f), (float)(IMG_H - 1));

        vbox[t] = make_float4(bx1, by1, bx2, by2);
        supp[t] = 0;
    }
    __syncthreads();

    // greedy NMS (legacy +1 IoU): sequential over i, parallel over j>i
    for (int i = 0; i < cnt; ++i) {
        if (!supp[i]) {
            const float4 bi = vbox[i];
            const float areai = (bi.z - bi.x + 1.0f) * (bi.w - bi.y + 1.0f);
            for (int t = i + 1 + tid; t < cnt; t += 64) {
                const float4 bj = vbox[t];
                const float areaj = (bj.z - bj.x + 1.0f) * (bj.w - bj.y + 1.0f);
                const float ltx = fmaxf(bi.x, bj.x);
                const float lty = fmaxf(bi.y, bj.y);
                const float rbx = fminf(bi.z, bj.z);
                const float rby = fminf(bi.w, bj.w);
                const float wq = fmaxf(rbx - ltx + 1.0f, 0.0f);
                const float hq = fmaxf(rby - lty + 1.0f, 0.0f);
                const float inter = wq * hq;
                const float iou = inter / (areai + areaj - inter);
                if (iou > NMS_THRESH) supp[t] = 1;
            }
        }
        __syncthreads();
    }

    // compact kept in rank order, cap at DET (lossless for global top-DET)
    if (tid == 0) {
        int c2 = 0;
        for (int r = 0; r < cnt && c2 < DET; ++r)
            if (!supp[r]) keptRank[c2++] = r;
        keptCnt = c2;
        gcnt[cls] = c2;
    }
    __syncthreads();

    const int kc = keptCnt;
    for (int t = tid; t < kc; t += 64) {
        const int r = keptRank[t];
        const int slot = cls * DET + t;
        const unsigned int bits = (unsigned int)(key[r] >> 16);  // score bits
        gkeys[slot] = ((unsigned long long)bits << 16) |
                      (unsigned long long)(65535 - slot);
        gboxes[slot] = vbox[r];
    }
}

// ---------------------------------------------------------------------------
// Kernel 3: tournament merge of 80 sorted kept-lists -> global top-100.
// 1 block x 256 threads: all stage the fixed slot array into LDS (garbage
// beyond gcnt[c] is never read), then wave 0 runs 100 rounds: lane owns
// classes {lane, lane+64}, heads cached in registers, 6-step shfl u64
// max all-reduce picks the global winner; winner lane advances its head from
// LDS. Box fetches deferred to one parallel batch after the loop.
// ---------------------------------------------------------------------------
__device__ inline unsigned long long shfl_xor_u64(unsigned long long v, int off) {
    const unsigned int lo = __shfl_xor((unsigned int)v, off);
    const unsigned int hi = __shfl_xor((unsigned int)(v >> 32), off);
    return ((unsigned long long)hi << 32) | lo;
}

__global__ __launch_bounds__(256) void
topk_merge_kernel(const unsigned long long* __restrict__ gkeys,
                  const float4* __restrict__ gboxes,
                  const int* __restrict__ gcnt,
                  float* __restrict__ out) {
    __shared__ unsigned long long keys[NCAND];   // 64000 B

    #pragma unroll 4
    for (int t = threadIdx.x; t < NCAND; t += 256) keys[t] = gkeys[t];
    __syncthreads();
    if (threadIdx.x >= 64) return;

    const int lane = threadIdx.x;
    const int cA = lane;                 // every lane owns class lane
    const int cB = 64 + lane;            // lanes 0..15 own a second class
    const int kcA = gcnt[cA];
    const int kcB = (cB < CF) ? gcnt[cB] : 0;
    int hA = 0, hB = 0;
    unsigned long long kA = (kcA > 0) ? keys[cA * DET] : 0ull;
    unsigned long long kB = (kcB > 0) ? keys[cB * DET] : 0ull;

    unsigned long long w0k = 0ull, w1k = 0ull;
    int w0s = 0, w1s = 0;

    for (int r = 0; r < DET; ++r) {
        unsigned long long m = (kA >= kB) ? kA : kB;
        #pragma unroll
        for (int off = 32; off > 0; off >>= 1) {
            const unsigned long long o = shfl_xor_u64(m, off);
            if (o > m) m = o;
        }
        if (m == 0ull) break;                     // uniform: no candidates left

        const int wslot = 65535 - (int)(m & 0xFFFFull);
        const int wcls  = wslot / DET;
        if (wcls == cA)      { ++hA; kA = (hA < kcA) ? keys[cA * DET + hA] : 0ull; }
        else if (wcls == cB) { ++hB; kB = (hB < kcB) ? keys[cB * DET + hB] : 0ull; }

        if (lane == (r & 63)) {
            if (r < 64) { w0k = m; w0s = wslot; }
            else        { w1k = m; w1s = wslot; }
        }
    }

    // output: lane l holds global ranks l (w0) and 64+l (w1)
    if (w0k != 0ull) {
        const float4 b = gboxes[w0s];
        const int r = lane;
        out[r * 4 + 0] = b.x; out[r * 4 + 1] = b.y;
        out[r * 4 + 2] = b.z; out[r * 4 + 3] = b.w;
        out[4 * DET + r] = __uint_as_float((unsigned int)(w0k >> 16));
        out[5 * DET + r] = (float)(w0s / DET + 1);
    }
    if (w1k != 0ull) {
        const float4 b = gboxes[w1s];
        const int r = 64 + lane;
        out[r * 4 + 0] = b.x; out[r * 4 + 1] = b.y;
        out[r * 4 + 2] = b.z; out[r * 4 + 3] = b.w;
        out[4 * DET + r] = __uint_as_float((unsigned int)(w1k >> 16));
        out[5 * DET + r] = (float)(w1s / DET + 1);
    }
}

// ---------------------------------------------------------------------------
extern "C" void kernel_launch(void* const* d_in, const int* in_sizes, int n_in,
                              void* d_out, int out_size, void* d_ws, size_t ws_size,
                              hipStream_t stream) {
    (void)in_sizes; (void)n_in; (void)out_size; (void)ws_size;

    const float* class_logits   = (const float*)d_in[0];  // [NP, NC]
    const float* box_regression = (const float*)d_in[1];  // [NP, 4*NC]
    const float* proposals      = (const float*)d_in[2];  // [NP, 4]
    float* out = (float*)d_out;                           // 600 floats

    // Workspace layout (float units; all offsets 16B-aligned)
    float* ws        = (float*)d_ws;
    float* gboxes_f  = ws;                                    // NCAND*4 = 32000
    float* gkeys_f   = gboxes_f + (size_t)NCAND * 4;          // NCAND*2 = 16000
    float* scores_fg = gkeys_f + (size_t)NCAND * 2;           // CF*NP   = 81920
    int*   gcnt      = (int*)(scores_fg + (size_t)CF * NP);   // CF

    unsigned long long* gkeys = (unsigned long long*)gkeys_f;
    float4* gboxes = (float4*)gboxes_f;

    softmax_kernel<<<dim3(NP / 4), dim3(256), 0, stream>>>(
        class_logits, scores_fg, out);

    class_nms_kernel<<<dim3(CF), dim3(64), 0, stream>>>(
        scores_fg, box_regression, proposals, gkeys, gboxes, gcnt);

    topk_merge_kernel<<<dim3(1), dim3(256), 0, stream>>>(
        gkeys, gboxes, gcnt, out);
}

// Round 5
// 115.360 us; speedup vs baseline: 1.3715x; 1.0892x over previous
//
#include <hip/hip_runtime.h>
#include <hip/hip_bf16.h>
#include <math.h>

#define NP 1024          // proposals
#define NC 81            // classes incl background
#define CF 80            // foreground classes
#define DET 100          // detections per image
#define SCORE_THRESH 0.05f
#define NMS_THRESH 0.5f
#define BBOX_CLIP 4.135166556742356f   // log(1000/16)
#define IMG_W 1333
#define IMG_H 800

#define NCAND (CF * DET)   // 8000 max compacted candidates

// ---------------------------------------------------------------------------
// Kernel 1: per-proposal softmax scores. One wave per proposal, 4/block.
// scores_fg class-major [c][i]. Also zeroes d_out, gK, and gkeys[0..NCAND)
// (zero keys make kernel 3's padded rank loop inert).
// ---------------------------------------------------------------------------
__global__ __launch_bounds__(256) void
softmax_kernel(const float* __restrict__ logits,
               float* __restrict__ scores_fg,
               unsigned long long* __restrict__ gkeys,
               float* __restrict__ out,
               int* __restrict__ gK) {
    {
        const int gid = blockIdx.x * 256 + threadIdx.x;   // 0..65535
        if (gid < NCAND) gkeys[gid] = 0ull;
    }
    if (blockIdx.x == 0) {
        for (int t = threadIdx.x; t < 6 * DET; t += 256) out[t] = 0.0f;
        if (threadIdx.x == 0) *gK = 0;
    }

    const int wave = threadIdx.x >> 6;
    const int lane = threadIdx.x & 63;
    const int i = blockIdx.x * 4 + wave;          // proposal index

    const float x0 = logits[i * NC + lane];
    const float x1 = (lane < NC - 64) ? logits[i * NC + 64 + lane] : -INFINITY;

    float m = fmaxf(x0, x1);
    for (int off = 32; off > 0; off >>= 1) m = fmaxf(m, __shfl_xor(m, off));

    const float e0 = expf(x0 - m);
    const float e1 = (lane < NC - 64) ? expf(x1 - m) : 0.0f;
    float sum = e0 + e1;
    for (int off = 32; off > 0; off >>= 1) sum += __shfl_xor(sum, off);

    if (lane >= 1) scores_fg[(lane - 1) * NP + i] = e0 / sum;
    if (lane < NC - 64) scores_fg[(64 + lane - 1) * NP + i] = e1 / sum;
}

// ---------------------------------------------------------------------------
// Kernel 2: per-class threshold-compact -> u64-key bitonic sort -> on-demand
// box decode -> greedy NMS -> atomically append kept (<=DET) to the global
// candidate list (dense prefix of gkeys/gboxes, length gK).
// Key = (score_bits<<16)|(65535-slot), slot = cls*DET + keptRank:
// order-isomorphic to the reference's (score desc, flat-index asc) tie-break.
// Single wave per class block.
// ---------------------------------------------------------------------------
__global__ __launch_bounds__(64) void
class_nms_kernel(const float* __restrict__ scores_fg,
                 const float* __restrict__ rel,
                 const float* __restrict__ props,
                 unsigned long long* __restrict__ gkeys,
                 float4* __restrict__ gboxes,
                 int* __restrict__ gK) {
    const int cls = blockIdx.x;   // fg class (reference class = cls+1)
    const int tid = threadIdx.x;  // 0..63

    __shared__ unsigned long long key[NP];
    __shared__ float4             vbox[NP];
    __shared__ unsigned char      supp[NP];
    __shared__ int                cntSh;
    __shared__ int                keptRank[DET];
    __shared__ int                keptCnt;
    __shared__ int                baseSh;

    if (tid == 0) cntSh = 0;
    __syncthreads();

    // threshold compaction: 1024 scores, 4 float4 per lane
    const float4* srow = (const float4*)(scores_fg + cls * NP);
    #pragma unroll
    for (int k = 0; k < 4; ++k) {
        const int idx4 = k * 64 + tid;
        const float4 v = srow[idx4];
        const int id0 = idx4 * 4;
        if (v.x > SCORE_THRESH) { int p = atomicAdd(&cntSh, 1); key[p] = ((unsigned long long)__float_as_uint(v.x) << 16) | (unsigned long long)(1023 - (id0 + 0)); }
        if (v.y > SCORE_THRESH) { int p = atomicAdd(&cntSh, 1); key[p] = ((unsigned long long)__float_as_uint(v.y) << 16) | (unsigned long long)(1023 - (id0 + 1)); }
        if (v.z > SCORE_THRESH) { int p = atomicAdd(&cntSh, 1); key[p] = ((unsigned long long)__float_as_uint(v.z) << 16) | (unsigned long long)(1023 - (id0 + 2)); }
        if (v.w > SCORE_THRESH) { int p = atomicAdd(&cntSh, 1); key[p] = ((unsigned long long)__float_as_uint(v.w) << 16) | (unsigned long long)(1023 - (id0 + 3)); }
    }
    __syncthreads();
    const int cnt = cntSh;

    // next pow2 >= cnt, pad with 0 (real keys have score bits set -> sort last)
    int msz = 1;
    while (msz < cnt) msz <<= 1;
    for (int t = cnt + tid; t < msz; t += 64) key[t] = 0ull;
    __syncthreads();

    // bitonic sort descending (u64 key encodes score desc, id asc)
    for (int k = 2; k <= msz; k <<= 1) {
        for (int jj = k >> 1; jj > 0; jj >>= 1) {
            for (int t = tid; t < msz; t += 64) {
                const int ixj = t ^ jj;
                if (ixj > t) {
                    const unsigned long long a = key[t], b = key[ixj];
                    const bool tAfter = (a < b);              // desc order
                    const bool dirAsc = ((t & k) == 0);
                    if (dirAsc ? tAfter : !tAfter) { key[t] = b; key[ixj] = a; }
                }
            }
            __syncthreads();
        }
    }

    // on-demand box decode for survivors (exact reference formulas)
    for (int t = tid; t < cnt; t += 64) {
        const int id = 1023 - (int)(key[t] & 0xFFFFull);     // proposal index
        const float4 p = ((const float4*)props)[id];
        const float w  = p.z - p.x + 1.0f;
        const float h  = p.w - p.y + 1.0f;
        const float cx = p.x + 0.5f * w;
        const float cy = p.y + 0.5f * h;

        const float4 r = ((const float4*)rel)[id * NC + (cls + 1)];
        const float dx = r.x / 10.0f;
        const float dy = r.y / 10.0f;
        const float dw = fminf(r.z / 5.0f, BBOX_CLIP);
        const float dh = fminf(r.w / 5.0f, BBOX_CLIP);

        const float pcx = dx * w + cx;
        const float pcy = dy * h + cy;
        const float pw  = expf(dw) * w;
        const float ph  = expf(dh) * h;

        float bx1 = pcx - 0.5f * pw;
        float by1 = pcy - 0.5f * ph;
        float bx2 = pcx + 0.5f * pw - 1.0f;
        float by2 = pcy + 0.5f * ph - 1.0f;

        bx1 = fminf(fmaxf(bx1, 0.0f), (float)(IMG_W - 1));
        bx2 = fminf(fmaxf(bx2, 0.0f), (float)(IMG_W - 1));
        by1 = fminf(fmaxf(by1, 0.0f), (float)(IMG_H - 1));
        by2 = fminf(fmaxf(by2, 0.0f), (float)(IMG_H - 1));

        vbox[t] = make_float4(bx1, by1, bx2, by2);
        supp[t] = 0;
    }
    __syncthreads();

    // greedy NMS (legacy +1 IoU): sequential over i, parallel over j>i
    for (int i = 0; i < cnt; ++i) {
        if (!supp[i]) {
            const float4 bi = vbox[i];
            const float areai = (bi.z - bi.x + 1.0f) * (bi.w - bi.y + 1.0f);
            for (int t = i + 1 + tid; t < cnt; t += 64) {
                const float4 bj = vbox[t];
                const float areaj = (bj.z - bj.x + 1.0f) * (bj.w - bj.y + 1.0f);
                const float ltx = fmaxf(bi.x, bj.x);
                const float lty = fmaxf(bi.y, bj.y);
                const float rbx = fminf(bi.z, bj.z);
                const float rby = fminf(bi.w, bj.w);
                const float wq = fmaxf(rbx - ltx + 1.0f, 0.0f);
                const float hq = fmaxf(rby - lty + 1.0f, 0.0f);
                const float inter = wq * hq;
                const float iou = inter / (areai + areaj - inter);
                if (iou > NMS_THRESH) supp[t] = 1;
            }
        }
        __syncthreads();
    }

    // compact kept in rank order, cap at DET (lossless for global top-DET)
    if (tid == 0) {
        int c2 = 0;
        for (int r = 0; r < cnt && c2 < DET; ++r)
            if (!supp[r]) keptRank[c2++] = r;
        keptCnt = c2;
        baseSh = atomicAdd(gK, c2);     // device-scope dense append
    }
    __syncthreads();

    const int kc = keptCnt, base = baseSh;
    for (int t = tid; t < kc; t += 64) {
        const int r = keptRank[t];
        const int slot = cls * DET + t;
        const unsigned int bits = (unsigned int)(key[r] >> 16);  // score bits
        gkeys[base + t] = ((unsigned long long)bits << 16) |
                          (unsigned long long)(65535 - slot);
        gboxes[base + t] = vbox[r];
    }
}

// ---------------------------------------------------------------------------
// Kernel 3: rank-count top-DET over the K compacted candidates.
// 125 blocks x 64 threads; each active block stages all K keys into LDS
// (coalesced), then each lane computes rank = #{key_j > key_mine} with an
// explicit 16-deep software pipeline: 16 independent ds_read_b64 into a
// fully-unrolled register array, ONE lgkmcnt wait, 16 compares. This breaks
// the dependent-LDS-read chain that made the R2 version 45 us.
// gkeys[K..) is zero (kernel 1), so the padded tail is rank-inert.
// Ranks are dense & unique -> exactly one writer per output slot.
// ---------------------------------------------------------------------------
__global__ __launch_bounds__(64) void
topk_rank_kernel(const unsigned long long* __restrict__ gkeys,
                 const float4* __restrict__ gboxes,
                 const int* __restrict__ gK,
                 float* __restrict__ out) {
    const int K = *gK;
    const int g = blockIdx.x * 64 + threadIdx.x;
    if (blockIdx.x * 64 >= K) return;

    __shared__ __align__(16) unsigned long long keysh[NCAND];

    const int Kpad = (K + 15) & ~15;
    for (int t = threadIdx.x; t < Kpad; t += 64) keysh[t] = gkeys[t];
    __syncthreads();

    if (g >= K) return;
    const unsigned long long my = keysh[g];

    int rank = 0;
    for (int j = 0; j < Kpad; j += 16) {
        unsigned long long kk[16];
        #pragma unroll
        for (int u = 0; u < 16; ++u) kk[u] = keysh[j + u];   // 16 indep ds_read
        #pragma unroll
        for (int u = 0; u < 16; ++u) rank += (kk[u] > my) ? 1 : 0;
    }

    if (rank < DET) {
        const float sc  = __uint_as_float((unsigned)(my >> 16));
        const int  slot = 65535 - (int)(my & 0xFFFFull);
        const float4 b = gboxes[g];
        out[rank * 4 + 0] = b.x;
        out[rank * 4 + 1] = b.y;
        out[rank * 4 + 2] = b.z;
        out[rank * 4 + 3] = b.w;
        out[4 * DET + rank] = sc;                       // score (>0 always)
        out[5 * DET + rank] = (float)(slot / DET + 1);  // label
    }
}

// ---------------------------------------------------------------------------
extern "C" void kernel_launch(void* const* d_in, const int* in_sizes, int n_in,
                              void* d_out, int out_size, void* d_ws, size_t ws_size,
                              hipStream_t stream) {
    (void)in_sizes; (void)n_in; (void)out_size; (void)ws_size;

    const float* class_logits   = (const float*)d_in[0];  // [NP, NC]
    const float* box_regression = (const float*)d_in[1];  // [NP, 4*NC]
    const float* proposals      = (const float*)d_in[2];  // [NP, 4]
    float* out = (float*)d_out;                           // 600 floats

    // Workspace layout (float units; all offsets 16B-aligned)
    float* ws        = (float*)d_ws;
    float* gboxes_f  = ws;                                    // NCAND*4 = 32000
    float* gkeys_f   = gboxes_f + (size_t)NCAND * 4;          // NCAND*2 = 16000
    float* scores_fg = gkeys_f + (size_t)NCAND * 2;           // CF*NP   = 81920
    int*   gK        = (int*)(scores_fg + (size_t)CF * NP);   // 1

    unsigned long long* gkeys = (unsigned long long*)gkeys_f;
    float4* gboxes = (float4*)gboxes_f;

    softmax_kernel<<<dim3(NP / 4), dim3(256), 0, stream>>>(
        class_logits, scores_fg, gkeys, out, gK);

    class_nms_kernel<<<dim3(CF), dim3(64), 0, stream>>>(
        scores_fg, box_regression, proposals, gkeys, gboxes, gK);

    topk_rank_kernel<<<dim3((NCAND + 63) / 64), dim3(64), 0, stream>>>(
        gkeys, gboxes, gK, out);
}

// Round 6
// 102.421 us; speedup vs baseline: 1.5448x; 1.1263x over previous
//
#include <hip/hip_runtime.h>
#include <hip/hip_bf16.h>
#include <math.h>

#define NP 1024          // proposals
#define NC 81            // classes incl background
#define CF 80            // foreground classes
#define DET 100          // detections per image
#define SCORE_THRESH 0.05f
#define NMS_THRESH 0.5f
#define BBOX_CLIP 4.135166556742356f   // log(1000/16)
#define IMG_W 1333
#define IMG_H 800

#define NCAND (CF * DET)   // 8000 max compacted candidates

// ---------------------------------------------------------------------------
// Kernel 1: per-proposal softmax scores. One wave per proposal, 4/block.
// scores_fg class-major [c][i]. Block 0 zeroes d_out and gK.
// (Summation tree association matches the reference bit-exactly — proven
// absmax 0.0 in R1..R5. Do not change any float op here.)
// ---------------------------------------------------------------------------
__global__ __launch_bounds__(256) void
softmax_kernel(const float* __restrict__ logits,
               float* __restrict__ scores_fg,
               float* __restrict__ out,
               int* __restrict__ gK) {
    if (blockIdx.x == 0) {
        for (int t = threadIdx.x; t < 6 * DET; t += 256) out[t] = 0.0f;
        if (threadIdx.x == 0) *gK = 0;
    }

    const int wave = threadIdx.x >> 6;
    const int lane = threadIdx.x & 63;
    const int i = blockIdx.x * 4 + wave;          // proposal index

    const float x0 = logits[i * NC + lane];
    const float x1 = (lane < NC - 64) ? logits[i * NC + 64 + lane] : -INFINITY;

    float m = fmaxf(x0, x1);
    for (int off = 32; off > 0; off >>= 1) m = fmaxf(m, __shfl_xor(m, off));

    const float e0 = expf(x0 - m);
    const float e1 = (lane < NC - 64) ? expf(x1 - m) : 0.0f;
    float sum = e0 + e1;
    for (int off = 32; off > 0; off >>= 1) sum += __shfl_xor(sum, off);

    if (lane >= 1) scores_fg[(lane - 1) * NP + i] = e0 / sum;
    if (lane < NC - 64) scores_fg[(64 + lane - 1) * NP + i] = e1 / sum;
}

// ---------------------------------------------------------------------------
// Kernel 2: per-class threshold-compact -> u64-key bitonic sort -> on-demand
// box decode -> greedy NMS -> atomic append kept (<=DET) to global list.
// Key = (score_bits<<16)|(65535-slot), slot = cls*DET + keptRank: order-
// isomorphic to the reference's (score desc, flat-index asc) tie-break.
// NMS fast path (cnt<=64): lane j precomputes a 64-bit "suppressed-by-i"
// mask (identical per-pair float ops, no barriers), then a ~cnt-step scalar
// ballot resolve. Fallback to the barrier loop for cnt>64.
// Single wave per class block.
// ---------------------------------------------------------------------------
__global__ __launch_bounds__(64) void
class_nms_kernel(const float* __restrict__ scores_fg,
                 const float* __restrict__ rel,
                 const float* __restrict__ props,
                 unsigned long long* __restrict__ gkeys,
                 float4* __restrict__ gboxes,
                 int* __restrict__ gK) {
    const int cls = blockIdx.x;   // fg class (reference class = cls+1)
    const int tid = threadIdx.x;  // 0..63

    __shared__ unsigned long long key[NP];
    __shared__ float4             vbox[NP];
    __shared__ unsigned char      supp[NP];
    __shared__ int                cntSh;
    __shared__ int                keptRank[DET];
    __shared__ int                keptCnt;
    __shared__ int                baseSh;

    if (tid == 0) cntSh = 0;
    __syncthreads();

    // threshold compaction: 1024 scores, 4 float4 per lane
    const float4* srow = (const float4*)(scores_fg + cls * NP);
    #pragma unroll
    for (int k = 0; k < 4; ++k) {
        const int idx4 = k * 64 + tid;
        const float4 v = srow[idx4];
        const int id0 = idx4 * 4;
        if (v.x > SCORE_THRESH) { int p = atomicAdd(&cntSh, 1); key[p] = ((unsigned long long)__float_as_uint(v.x) << 16) | (unsigned long long)(1023 - (id0 + 0)); }
        if (v.y > SCORE_THRESH) { int p = atomicAdd(&cntSh, 1); key[p] = ((unsigned long long)__float_as_uint(v.y) << 16) | (unsigned long long)(1023 - (id0 + 1)); }
        if (v.z > SCORE_THRESH) { int p = atomicAdd(&cntSh, 1); key[p] = ((unsigned long long)__float_as_uint(v.z) << 16) | (unsigned long long)(1023 - (id0 + 2)); }
        if (v.w > SCORE_THRESH) { int p = atomicAdd(&cntSh, 1); key[p] = ((unsigned long long)__float_as_uint(v.w) << 16) | (unsigned long long)(1023 - (id0 + 3)); }
    }
    __syncthreads();
    const int cnt = cntSh;

    // next pow2 >= cnt, pad with 0 (real keys have score bits set -> sort last)
    int msz = 1;
    while (msz < cnt) msz <<= 1;
    for (int t = cnt + tid; t < msz; t += 64) key[t] = 0ull;
    __syncthreads();

    // bitonic sort descending (u64 key encodes score desc, id asc)
    for (int k = 2; k <= msz; k <<= 1) {
        for (int jj = k >> 1; jj > 0; jj >>= 1) {
            for (int t = tid; t < msz; t += 64) {
                const int ixj = t ^ jj;
                if (ixj > t) {
                    const unsigned long long a = key[t], b = key[ixj];
                    const bool tAfter = (a < b);              // desc order
                    const bool dirAsc = ((t & k) == 0);
                    if (dirAsc ? tAfter : !tAfter) { key[t] = b; key[ixj] = a; }
                }
            }
            __syncthreads();
        }
    }

    // on-demand box decode for survivors (exact reference formulas)
    for (int t = tid; t < cnt; t += 64) {
        const int id = 1023 - (int)(key[t] & 0xFFFFull);     // proposal index
        const float4 p = ((const float4*)props)[id];
        const float w  = p.z - p.x + 1.0f;
        const float h  = p.w - p.y + 1.0f;
        const float cx = p.x + 0.5f * w;
        const float cy = p.y + 0.5f * h;

        const float4 r = ((const float4*)rel)[id * NC + (cls + 1)];
        const float dx = r.x / 10.0f;
        const float dy = r.y / 10.0f;
        const float dw = fminf(r.z / 5.0f, BBOX_CLIP);
        const float dh = fminf(r.w / 5.0f, BBOX_CLIP);

        const float pcx = dx * w + cx;
        const float pcy = dy * h + cy;
        const float pw  = expf(dw) * w;
        const float ph  = expf(dh) * h;

        float bx1 = pcx - 0.5f * pw;
        float by1 = pcy - 0.5f * ph;
        float bx2 = pcx + 0.5f * pw - 1.0f;
        float by2 = pcy + 0.5f * ph - 1.0f;

        bx1 = fminf(fmaxf(bx1, 0.0f), (float)(IMG_W - 1));
        bx2 = fminf(fmaxf(bx2, 0.0f), (float)(IMG_W - 1));
        by1 = fminf(fmaxf(by1, 0.0f), (float)(IMG_H - 1));
        by2 = fminf(fmaxf(by2, 0.0f), (float)(IMG_H - 1));

        vbox[t] = make_float4(bx1, by1, bx2, by2);
        supp[t] = 0;
    }
    __syncthreads();

    if (cnt <= 64) {
        // ---- fast NMS: bitmask precompute + scalar ballot resolve ----
        unsigned long long mymask = 0ull;   // bit i: leader i suppresses me
        if (tid < cnt) {
            const float4 bj = vbox[tid];
            const float areaj = (bj.z - bj.x + 1.0f) * (bj.w - bj.y + 1.0f);
            for (int i = 0; i < tid; ++i) {           // only i < j can suppress
                const float4 bi = vbox[i];            // LDS broadcast read
                const float areai = (bi.z - bi.x + 1.0f) * (bi.w - bi.y + 1.0f);
                const float ltx = fmaxf(bi.x, bj.x);
                const float lty = fmaxf(bi.y, bj.y);
                const float rbx = fminf(bi.z, bj.z);
                const float rby = fminf(bi.w, bj.w);
                const float wq = fmaxf(rbx - ltx + 1.0f, 0.0f);
                const float hq = fmaxf(rby - lty + 1.0f, 0.0f);
                const float inter = wq * hq;
                const float iou = inter / (areai + areaj - inter);
                if (iou > NMS_THRESH) mymask |= (1ull << i);
            }
        }
        // greedy resolve: wave-uniform, no barriers
        unsigned long long suppbits = 0ull;
        for (int i = 0; i < cnt; ++i) {
            if (!((suppbits >> i) & 1ull)) {          // i is kept -> suppresses
                const unsigned long long vote = __ballot((mymask >> i) & 1ull);
                suppbits |= vote;
            }
        }
        if (tid < cnt) supp[tid] = (unsigned char)((suppbits >> tid) & 1ull);
        __syncthreads();
    } else {
        // ---- fallback: sequential-i barrier loop (any cnt) ----
        for (int i = 0; i < cnt; ++i) {
            if (!supp[i]) {
                const float4 bi = vbox[i];
                const float areai = (bi.z - bi.x + 1.0f) * (bi.w - bi.y + 1.0f);
                for (int t = i + 1 + tid; t < cnt; t += 64) {
                    const float4 bj = vbox[t];
                    const float areaj = (bj.z - bj.x + 1.0f) * (bj.w - bj.y + 1.0f);
                    const float ltx = fmaxf(bi.x, bj.x);
                    const float lty = fmaxf(bi.y, bj.y);
                    const float rbx = fminf(bi.z, bj.z);
                    const float rby = fminf(bi.w, bj.w);
                    const float wq = fmaxf(rbx - ltx + 1.0f, 0.0f);
                    const float hq = fmaxf(rby - lty + 1.0f, 0.0f);
                    const float inter = wq * hq;
                    const float iou = inter / (areai + areaj - inter);
                    if (iou > NMS_THRESH) supp[t] = 1;
                }
            }
            __syncthreads();
        }
    }

    // compact kept in rank order, cap at DET (lossless for global top-DET)
    if (tid == 0) {
        int c2 = 0;
        for (int r = 0; r < cnt && c2 < DET; ++r)
            if (!supp[r]) keptRank[c2++] = r;
        keptCnt = c2;
        baseSh = atomicAdd(gK, c2);     // device-scope dense append
    }
    __syncthreads();

    const int kc = keptCnt, base = baseSh;
    for (int t = tid; t < kc; t += 64) {
        const int r = keptRank[t];
        const int slot = cls * DET + t;
        const unsigned int bits = (unsigned int)(key[r] >> 16);  // score bits
        gkeys[base + t] = ((unsigned long long)bits << 16) |
                          (unsigned long long)(65535 - slot);
        gboxes[base + t] = vbox[r];
    }
}

// ---------------------------------------------------------------------------
// Kernel 3: rank-count top-DET over the K compacted candidates.
// 125 blocks x 64 threads (active blocks each on their own CU). Staging:
// 4 independent global loads per iteration (one waitcnt per 4), zero-fill
// tail to Kpad (real keys are nonzero -> pad is rank-inert). Scan: LDS as
// ulonglong2 (ds_read_b128), 8 reads = 16 keys per unrolled batch.
// Ranks are dense & unique -> exactly one writer per output slot.
// ---------------------------------------------------------------------------
__global__ __launch_bounds__(64) void
topk_rank_kernel(const unsigned long long* __restrict__ gkeys,
                 const float4* __restrict__ gboxes,
                 const int* __restrict__ gK,
                 float* __restrict__ out) {
    const int K = *gK;
    if ((int)blockIdx.x * 64 >= K) return;

    __shared__ __align__(16) unsigned long long keysh[NCAND + 16];
    const int Kpad = (K + 15) & ~15;

    int t = threadIdx.x;
    for (; t + 192 < Kpad; t += 256) {
        const unsigned long long a0 = (t       < K) ? gkeys[t]       : 0ull;
        const unsigned long long a1 = (t + 64  < K) ? gkeys[t + 64]  : 0ull;
        const unsigned long long a2 = (t + 128 < K) ? gkeys[t + 128] : 0ull;
        const unsigned long long a3 = (t + 192 < K) ? gkeys[t + 192] : 0ull;
        keysh[t]       = a0;
        keysh[t + 64]  = a1;
        keysh[t + 128] = a2;
        keysh[t + 192] = a3;
    }
    for (; t < Kpad; t += 64) keysh[t] = (t < K) ? gkeys[t] : 0ull;
    __syncthreads();

    const int g = blockIdx.x * 64 + threadIdx.x;
    if (g >= K) return;
    const unsigned long long my = keysh[g];

    const ulonglong2* kp = (const ulonglong2*)keysh;
    const int nb2 = Kpad >> 1;           // multiple of 8
    int rank = 0;
    for (int j = 0; j < nb2; j += 8) {
        ulonglong2 kk[8];
        #pragma unroll
        for (int u = 0; u < 8; ++u) kk[u] = kp[j + u];   // 8 indep ds_read_b128
        #pragma unroll
        for (int u = 0; u < 8; ++u) {
            rank += (kk[u].x > my) ? 1 : 0;
            rank += (kk[u].y > my) ? 1 : 0;
        }
    }

    if (rank < DET) {
        const float sc  = __uint_as_float((unsigned)(my >> 16));
        const int  slot = 65535 - (int)(my & 0xFFFFull);
        const float4 b = gboxes[g];
        out[rank * 4 + 0] = b.x;
        out[rank * 4 + 1] = b.y;
        out[rank * 4 + 2] = b.z;
        out[rank * 4 + 3] = b.w;
        out[4 * DET + rank] = sc;                       // score (>0 always)
        out[5 * DET + rank] = (float)(slot / DET + 1);  // label
    }
}

// ---------------------------------------------------------------------------
extern "C" void kernel_launch(void* const* d_in, const int* in_sizes, int n_in,
                              void* d_out, int out_size, void* d_ws, size_t ws_size,
                              hipStream_t stream) {
    (void)in_sizes; (void)n_in; (void)out_size; (void)ws_size;

    const float* class_logits   = (const float*)d_in[0];  // [NP, NC]
    const float* box_regression = (const float*)d_in[1];  // [NP, 4*NC]
    const float* proposals      = (const float*)d_in[2];  // [NP, 4]
    float* out = (float*)d_out;                           // 600 floats

    // Workspace layout (float units; all offsets 16B-aligned)
    float* ws        = (float*)d_ws;
    float* gboxes_f  = ws;                                    // NCAND*4 = 32000
    float* gkeys_f   = gboxes_f + (size_t)NCAND * 4;          // NCAND*2 = 16000
    float* scores_fg = gkeys_f + (size_t)NCAND * 2;           // CF*NP   = 81920
    int*   gK        = (int*)(scores_fg + (size_t)CF * NP);   // 1

    unsigned long long* gkeys = (unsigned long long*)gkeys_f;
    float4* gboxes = (float4*)gboxes_f;

    softmax_kernel<<<dim3(NP / 4), dim3(256), 0, stream>>>(
        class_logits, scores_fg, out, gK);

    class_nms_kernel<<<dim3(CF), dim3(64), 0, stream>>>(
        scores_fg, box_regression, proposals, gkeys, gboxes, gK);

    topk_rank_kernel<<<dim3((NCAND + 63) / 64), dim3(64), 0, stream>>>(
        gkeys, gboxes, gK, out);
}